// Round 7
// baseline (59.806 us; speedup 1.0000x reference)
//
#include <hip/hip_runtime.h>

#define H 2048
#define W 2048
#define NBINS 256
#define NIMG 6
#define NTILE 384            // 6 imgs * 64 tiles
#define IMGPX (H * W)

typedef unsigned int u32;
typedef unsigned char u8;
typedef float f32x4 __attribute__((ext_vector_type(4)));

// ---------------- Kernel 1: per-tile partial histograms ----------------
// 1536 blocks = 4 per tile (64 rows each). Wave-private LDS hists -> plain
// store of the block's partial histogram (no memset, no global atomics).
__global__ __launch_bounds__(256) void clahe_hist(const float* __restrict__ x,
                                                  u32* __restrict__ part) {
    int blk  = blockIdx.x;      // tile*4 + q
    int tile = blk >> 2;
    int q    = blk & 3;
    int tx   = tile & 7;
    int ty   = (tile >> 3) & 7;
    int img  = tile >> 6;
    const float* base = x + (size_t)img * IMGPX;
    int row0 = ty * 256 + q * 64;
    int col0 = tx * 256;

    __shared__ u32 lh[4][NBINS];
    int t = threadIdx.x;
    for (int i = t; i < 4 * NBINS; i += 256) ((u32*)lh)[i] = 0;
    __syncthreads();

    int w  = t >> 6;    // wave id 0..3
    int cg = t & 63;    // 64 lanes cover 256 cols via float4
    for (int it = 0; it < 16; ++it) {
        int row = row0 + w + 4 * it;
        size_t off = (size_t)row * W + col0 + cg * 4;
        float4 v = *(const float4*)(base + off);
        // hist bins = clip(floor(x*256), 0, 255); x >= 0 so trunc == floor
        int b0 = min((int)(v.x * 256.0f), 255);
        int b1 = min((int)(v.y * 256.0f), 255);
        int b2 = min((int)(v.z * 256.0f), 255);
        int b3 = min((int)(v.w * 256.0f), 255);
        atomicAdd(&lh[w][b0], 1u);
        atomicAdd(&lh[w][b1], 1u);
        atomicAdd(&lh[w][b2], 1u);
        atomicAdd(&lh[w][b3], 1u);
    }
    __syncthreads();
    part[(size_t)blk * NBINS + t] =
        lh[0][t] + lh[1][t] + lh[2][t] + lh[3][t];
}

// ---------------- Kernel 2: LUT build (in-block) + bilinear apply ----------
// Block = 128 cols x 64 rows (aligned so the (y0,x0) cell is constant).
// Wave w builds LUT w of the 4 needed (exact integer arithmetic in f32, so
// identical to a separate LUT kernel). x re-read is L3-hot (hist just
// streamed it; nt-stores keep `out` from evicting it).
__global__ __launch_bounds__(256) void clahe_apply(const float* __restrict__ x,
                                                   const u32* __restrict__ part,
                                                   float* __restrict__ out) {
    int rx  = blockIdx.x * 128;
    int ry  = blockIdx.y * 64;
    int img = blockIdx.z;

    int yc = ry + 32, xc = rx + 64;
    int y0 = min(max((int)floorf((yc + 0.5f) * (1.0f / 256.0f) - 0.5f), 0), 7);
    int x0 = min(max((int)floorf((xc + 0.5f) * (1.0f / 256.0f) - 0.5f), 0), 7);
    int y1 = min(y0 + 1, 7), x1 = min(x0 + 1, 7);

    __shared__ alignas(16) float s_lut[4][NBINS];

    int t = threadIdx.x;
    int w = t >> 6, lane = t & 63;

    // ---- wave w: build LUT for cell (w&2 ? y1 : y0, w&1 ? x1 : x0) ----
    {
        int tys = (w & 2) ? y1 : y0;
        int txs = (w & 1) ? x1 : x0;
        int tile = (img << 6) | (tys << 3) | txs;
        const u32* pb = part + (size_t)tile * 4 * NBINS;
        // lane handles bins 4*lane .. 4*lane+3
        uint4 q0 = *((const uint4*)(pb) + lane);
        uint4 q1 = *((const uint4*)(pb + NBINS) + lane);
        uint4 q2 = *((const uint4*)(pb + 2 * NBINS) + lane);
        uint4 q3 = *((const uint4*)(pb + 3 * NBINS) + lane);
        // counts <= 65536: exact in f32
        float v0 = fminf((float)(q0.x + q1.x + q2.x + q3.x), 10240.0f);
        float v1 = fminf((float)(q0.y + q1.y + q2.y + q3.y), 10240.0f);
        float v2 = fminf((float)(q0.z + q1.z + q2.z + q3.z), 10240.0f);
        float v3 = fminf((float)(q0.w + q1.w + q2.w + q3.w), 10240.0f);
        float c0 = v0, c1 = c0 + v1, c2 = c1 + v2, c3 = c2 + v3;
        // wave-wide exclusive scan of per-lane totals
        float s = c3;
        #pragma unroll
        for (int off = 1; off < 64; off <<= 1) {
            float n = __shfl_up(s, off, 64);
            if (lane >= off) s += n;
        }
        float excl = s - c3;
        float tot  = __shfl(s, 63, 64);
        float e = (65536.0f - tot) * (1.0f / 256.0f);   // excess/num_bins
        int bi = 4 * lane;
        const float sc = 255.0f / 65536.0f;
        f32x4 L;
        L.x = floorf(fminf(fmaxf((excl + c0 + (float)(bi + 1) * e) * sc, 0.0f), 255.0f));
        L.y = floorf(fminf(fmaxf((excl + c1 + (float)(bi + 2) * e) * sc, 0.0f), 255.0f));
        L.z = floorf(fminf(fmaxf((excl + c2 + (float)(bi + 3) * e) * sc, 0.0f), 255.0f));
        L.w = floorf(fminf(fmaxf((excl + c3 + (float)(bi + 4) * e) * sc, 0.0f), 255.0f));
        L *= (1.0f / 255.0f);                            // fold final /255
        ((f32x4*)s_lut[w])[lane] = L;
    }
    __syncthreads();

    const float* base  = x   + (size_t)img * IMGPX;
    float*       obase = out + (size_t)img * IMGPX;

    int cg = t & 31, rg = t >> 5;     // 32 lanes * 4 px = 128 cols; 8 rows/iter
    int col = rx + cg * 4;

    float fx0 = (float)x0;
    float wxa[4];
    #pragma unroll
    for (int k = 0; k < 4; ++k) {
        float xs = (col + k + 0.5f) * (1.0f / 256.0f) - 0.5f;
        xs = fminf(fmaxf(xs, 0.0f), 7.0f);
        wxa[k] = xs - fx0;
    }

    #pragma unroll
    for (int it = 0; it < 8; ++it) {
        int row = ry + rg + 8 * it;
        float ys = (row + 0.5f) * (1.0f / 256.0f) - 0.5f;
        ys = fminf(fmaxf(ys, 0.0f), 7.0f);
        float wy = ys - (float)y0;

        size_t off = (size_t)row * W + col;
        float4 v = *(const float4*)(base + off);
        float vv[4] = {v.x, v.y, v.z, v.w};

        float r[4];
        #pragma unroll
        for (int k = 0; k < 4; ++k) {
            int p = min((int)(vv[k] * 255.0f), 255);   // pbin
            float wx = wxa[k];
            float ix0 = (1.0f - wx) * s_lut[0][p] + wx * s_lut[1][p];
            float ix1 = (1.0f - wx) * s_lut[2][p] + wx * s_lut[3][p];
            r[k] = (1.0f - wy) * ix0 + wy * ix1;       // /255 folded in LUT
        }
        f32x4 o = {r[0], r[1], r[2], r[3]};
        __builtin_nontemporal_store(o, (f32x4*)(obase + off));
    }
}

extern "C" void kernel_launch(void* const* d_in, const int* in_sizes, int n_in,
                              void* d_out, int out_size, void* d_ws, size_t ws_size,
                              hipStream_t stream) {
    const float* x = (const float*)d_in[0];
    float* out = (float*)d_out;

    u32* part = (u32*)d_ws;   // 1536 * 256 * 4 = 1.57 MB

    clahe_hist<<<dim3(NTILE * 4), dim3(256), 0, stream>>>(x, part);
    clahe_apply<<<dim3(16, 32, NIMG), dim3(256), 0, stream>>>(x, part, out);
}

// Round 8
// 54.635 us; speedup vs baseline: 1.0947x; 1.0947x over previous
//
#include <hip/hip_runtime.h>

#define H 2048
#define W 2048
#define NBINS 256
#define NIMG 6
#define NTILE 384            // 6 imgs * 64 tiles
#define IMGPX (H * W)

typedef unsigned int u32;
typedef unsigned char u8;
typedef float f32x4 __attribute__((ext_vector_type(4)));

// ---------------- Kernel 1: per-tile partial histograms + pbin ----------------
// 1536 blocks = 4 per tile (64 rows each). Wave-private LDS hists -> plain
// store of the block's partial histogram. x loaded NONTEMPORAL (read exactly
// once in this pipeline; keep L2/L3 for pbin). pbin stored normally (re-read
// by apply, want it cache-resident).
__global__ __launch_bounds__(256) void clahe_hist(const float* __restrict__ x,
                                                  u32* __restrict__ part,
                                                  u8* __restrict__ pbin) {
    int blk  = blockIdx.x;      // tile*4 + q
    int tile = blk >> 2;
    int q    = blk & 3;
    int tx   = tile & 7;
    int ty   = (tile >> 3) & 7;
    int img  = tile >> 6;
    const float* base = x + (size_t)img * IMGPX;
    u8* pb = pbin + (size_t)img * IMGPX;
    int row0 = ty * 256 + q * 64;
    int col0 = tx * 256;

    __shared__ u32 lh[4][NBINS];
    int t = threadIdx.x;
    for (int i = t; i < 4 * NBINS; i += 256) ((u32*)lh)[i] = 0;
    __syncthreads();

    int w  = t >> 6;    // wave id 0..3
    int cg = t & 63;    // 64 lanes cover 256 cols via float4
    for (int it = 0; it < 16; ++it) {
        int row = row0 + w + 4 * it;
        size_t off = (size_t)row * W + col0 + cg * 4;
        f32x4 v = __builtin_nontemporal_load((const f32x4*)(base + off));
        // hist bins = clip(floor(x*256), 0, 255); x >= 0 so trunc == floor
        int b0 = min((int)(v.x * 256.0f), 255);
        int b1 = min((int)(v.y * 256.0f), 255);
        int b2 = min((int)(v.z * 256.0f), 255);
        int b3 = min((int)(v.w * 256.0f), 255);
        atomicAdd(&lh[w][b0], 1u);
        atomicAdd(&lh[w][b1], 1u);
        atomicAdd(&lh[w][b2], 1u);
        atomicAdd(&lh[w][b3], 1u);
        // pbin = clip(floor(x*255), 0, 255)
        u32 p0 = min((int)(v.x * 255.0f), 255);
        u32 p1 = min((int)(v.y * 255.0f), 255);
        u32 p2 = min((int)(v.z * 255.0f), 255);
        u32 p3 = min((int)(v.w * 255.0f), 255);
        *(u32*)(pb + off) = p0 | (p1 << 8) | (p2 << 16) | (p3 << 24);
    }
    __syncthreads();
    part[(size_t)blk * NBINS + t] =
        lh[0][t] + lh[1][t] + lh[2][t] + lh[3][t];
}

// ---------------- Kernel 2: in-block LUT build + bilinear apply ----------
// Block = 128 cols x 64 rows (aligned so the (y0,x0) cell is constant).
// Wave w builds the LUT of cell w (exact integer arithmetic in f32 — verified
// identical to the separate LUT kernel in R7). LUT stored QUAD-INTERLEAVED:
// s_lutq[bin] = {l00,l01,l10,l11} -> one ds_read_b128 per pixel.
__global__ __launch_bounds__(256) void clahe_apply(const u8* __restrict__ pbin,
                                                   const u32* __restrict__ part,
                                                   float* __restrict__ out) {
    int rx  = blockIdx.x * 128;
    int ry  = blockIdx.y * 64;
    int img = blockIdx.z;

    int yc = ry + 32, xc = rx + 64;
    int y0 = min(max((int)floorf((yc + 0.5f) * (1.0f / 256.0f) - 0.5f), 0), 7);
    int x0 = min(max((int)floorf((xc + 0.5f) * (1.0f / 256.0f) - 0.5f), 0), 7);
    int y1 = min(y0 + 1, 7), x1 = min(x0 + 1, 7);

    __shared__ alignas(16) float s_lutq[NBINS][4];

    int t = threadIdx.x;
    int w = t >> 6, lane = t & 63;

    // ---- wave w: LUT for cell w: (w&2 ? y1 : y0, w&1 ? x1 : x0) ----
    {
        int tys = (w & 2) ? y1 : y0;
        int txs = (w & 1) ? x1 : x0;
        int tile = (img << 6) | (tys << 3) | txs;
        const u32* pb = part + (size_t)tile * 4 * NBINS;
        // lane handles bins 4*lane .. 4*lane+3
        uint4 q0 = *((const uint4*)(pb) + lane);
        uint4 q1 = *((const uint4*)(pb + NBINS) + lane);
        uint4 q2 = *((const uint4*)(pb + 2 * NBINS) + lane);
        uint4 q3 = *((const uint4*)(pb + 3 * NBINS) + lane);
        // counts <= 65536: exact in f32
        float v0 = fminf((float)(q0.x + q1.x + q2.x + q3.x), 10240.0f);
        float v1 = fminf((float)(q0.y + q1.y + q2.y + q3.y), 10240.0f);
        float v2 = fminf((float)(q0.z + q1.z + q2.z + q3.z), 10240.0f);
        float v3 = fminf((float)(q0.w + q1.w + q2.w + q3.w), 10240.0f);
        float c0 = v0, c1 = c0 + v1, c2 = c1 + v2, c3 = c2 + v3;
        // wave-wide scan of per-lane totals
        float s = c3;
        #pragma unroll
        for (int off = 1; off < 64; off <<= 1) {
            float n = __shfl_up(s, off, 64);
            if (lane >= off) s += n;
        }
        float excl = s - c3;
        float tot  = __shfl(s, 63, 64);
        float e = (65536.0f - tot) * (1.0f / 256.0f);   // excess/num_bins
        int bi = 4 * lane;
        const float sc = 255.0f / 65536.0f;
        float L0 = floorf(fminf(fmaxf((excl + c0 + (float)(bi + 1) * e) * sc, 0.0f), 255.0f));
        float L1 = floorf(fminf(fmaxf((excl + c1 + (float)(bi + 2) * e) * sc, 0.0f), 255.0f));
        float L2 = floorf(fminf(fmaxf((excl + c2 + (float)(bi + 3) * e) * sc, 0.0f), 255.0f));
        float L3 = floorf(fminf(fmaxf((excl + c3 + (float)(bi + 4) * e) * sc, 0.0f), 255.0f));
        const float inv = 1.0f / 255.0f;                 // fold final /255
        s_lutq[bi + 0][w] = L0 * inv;
        s_lutq[bi + 1][w] = L1 * inv;
        s_lutq[bi + 2][w] = L2 * inv;
        s_lutq[bi + 3][w] = L3 * inv;
    }
    __syncthreads();

    const u8* pbase = pbin + (size_t)img * IMGPX;
    float*    obase = out  + (size_t)img * IMGPX;

    int cg = t & 31, rg = t >> 5;     // 32 lanes * 4 px = 128 cols; 8 rows/iter
    int col = rx + cg * 4;

    float fx0 = (float)x0;
    float wxa[4];
    #pragma unroll
    for (int k = 0; k < 4; ++k) {
        float xs = (col + k + 0.5f) * (1.0f / 256.0f) - 0.5f;
        xs = fminf(fmaxf(xs, 0.0f), 7.0f);
        wxa[k] = xs - fx0;
    }

    #pragma unroll
    for (int it = 0; it < 8; ++it) {
        int row = ry + rg + 8 * it;
        float ys = (row + 0.5f) * (1.0f / 256.0f) - 0.5f;
        ys = fminf(fmaxf(ys, 0.0f), 7.0f);
        float wy = ys - (float)y0;

        size_t off = (size_t)row * W + col;
        u32 pw = *(const u32*)(pbase + off);

        float r[4];
        #pragma unroll
        for (int k = 0; k < 4; ++k) {
            int p = (pw >> (8 * k)) & 255;
            f32x4 L = *((const f32x4*)s_lutq + p);      // one ds_read_b128
            float wx = wxa[k];
            float ix0 = (1.0f - wx) * L.x + wx * L.y;   // y0 row
            float ix1 = (1.0f - wx) * L.z + wx * L.w;   // y1 row
            r[k] = (1.0f - wy) * ix0 + wy * ix1;        // /255 folded in LUT
        }
        f32x4 o = {r[0], r[1], r[2], r[3]};
        __builtin_nontemporal_store(o, (f32x4*)(obase + off));
    }
}

extern "C" void kernel_launch(void* const* d_in, const int* in_sizes, int n_in,
                              void* d_out, int out_size, void* d_ws, size_t ws_size,
                              hipStream_t stream) {
    const float* x = (const float*)d_in[0];
    float* out = (float*)d_out;

    const size_t PBIN_BYTES = (size_t)NIMG * IMGPX;           // 25.17 MB
    u8*  pbin = (u8*)d_ws;
    u32* part = (u32*)((char*)d_ws + PBIN_BYTES);             // 1.57 MB

    clahe_hist<<<dim3(NTILE * 4), dim3(256), 0, stream>>>(x, part, pbin);
    clahe_apply<<<dim3(16, 32, NIMG), dim3(256), 0, stream>>>(pbin, part, out);
}

// Round 9
// 51.369 us; speedup vs baseline: 1.1642x; 1.0636x over previous
//
#include <hip/hip_runtime.h>

#define H 2048
#define W 2048
#define NBINS 256
#define NIMG 6
#define NTILE 384            // 6 imgs * 64 tiles
#define IMGPX (H * W)

typedef unsigned int u32;
typedef unsigned char u8;
typedef float f32x4 __attribute__((ext_vector_type(4)));

// ---------------- Kernel 1: per-tile partial histograms + pbin ----------------
// 1536 blocks = 4 per tile (64 rows each). Wave-private LDS hists -> plain
// store of the block's partial histogram. x loaded NONTEMPORAL (read exactly
// once; keep cache for pbin). pbin stored normally (re-read by apply).
__global__ __launch_bounds__(256) void clahe_hist(const float* __restrict__ x,
                                                  u32* __restrict__ part,
                                                  u8* __restrict__ pbin) {
    int blk  = blockIdx.x;      // tile*4 + q
    int tile = blk >> 2;
    int q    = blk & 3;
    int tx   = tile & 7;
    int ty   = (tile >> 3) & 7;
    int img  = tile >> 6;
    const float* base = x + (size_t)img * IMGPX;
    u8* pb = pbin + (size_t)img * IMGPX;
    int row0 = ty * 256 + q * 64;
    int col0 = tx * 256;

    __shared__ u32 lh[4][NBINS];
    int t = threadIdx.x;
    for (int i = t; i < 4 * NBINS; i += 256) ((u32*)lh)[i] = 0;
    __syncthreads();

    int w  = t >> 6;    // wave id 0..3
    int cg = t & 63;    // 64 lanes cover 256 cols via float4
    for (int it = 0; it < 16; ++it) {
        int row = row0 + w + 4 * it;
        size_t off = (size_t)row * W + col0 + cg * 4;
        f32x4 v = __builtin_nontemporal_load((const f32x4*)(base + off));
        // hist bins = clip(floor(x*256), 0, 255); x >= 0 so trunc == floor
        int b0 = min((int)(v.x * 256.0f), 255);
        int b1 = min((int)(v.y * 256.0f), 255);
        int b2 = min((int)(v.z * 256.0f), 255);
        int b3 = min((int)(v.w * 256.0f), 255);
        atomicAdd(&lh[w][b0], 1u);
        atomicAdd(&lh[w][b1], 1u);
        atomicAdd(&lh[w][b2], 1u);
        atomicAdd(&lh[w][b3], 1u);
        // pbin = clip(floor(x*255), 0, 255)
        u32 p0 = min((int)(v.x * 255.0f), 255);
        u32 p1 = min((int)(v.y * 255.0f), 255);
        u32 p2 = min((int)(v.z * 255.0f), 255);
        u32 p3 = min((int)(v.w * 255.0f), 255);
        *(u32*)(pb + off) = p0 | (p1 << 8) | (p2 << 16) | (p3 << 24);
    }
    __syncthreads();
    part[(size_t)blk * NBINS + t] =
        lh[0][t] + lh[1][t] + lh[2][t] + lh[3][t];
}

// ---------------- Kernel 2: sum partials, clip + cumsum -> u8 LUT ------------
// One block (256 threads) per tile; thread t owns bin t. LUT values are
// integers 0..255 -> store as u8 (apply packs 4 of them into one u32).
__global__ __launch_bounds__(256) void clahe_lut(const u32* __restrict__ part,
                                                 u8* __restrict__ luts8) {
    int tile = blockIdx.x;
    int t = threadIdx.x;
    const u32* p = part + (size_t)tile * 4 * NBINS;
    float h = (float)(p[t] + p[NBINS + t] + p[2 * NBINS + t] + p[3 * NBINS + t]);
    float v = fminf(h, 10240.0f);   // max_val = max(int(40*65536)//256, 1)

    int lane = t & 63, wid = t >> 6;
    #pragma unroll
    for (int off = 1; off < 64; off <<= 1) {
        float n = __shfl_up(v, off, 64);
        if (lane >= off) v += n;
    }
    __shared__ float wsum[4];
    __shared__ float tot;
    if (lane == 63) wsum[wid] = v;
    __syncthreads();
    float add = 0.0f;
    for (int ww = 0; ww < wid; ++ww) add += wsum[ww];
    v += add;                        // inclusive cumsum of clipped
    if (t == 255) tot = v;
    __syncthreads();

    float e   = (65536.0f - tot) * (1.0f / 256.0f);   // excess/num_bins
    float cum = v + (float)(t + 1) * e;               // cumsum(clipped + e)
    float lut = floorf(fminf(fmaxf(cum * (255.0f / 65536.0f), 0.0f), 255.0f));
    luts8[(size_t)tile * NBINS + t] = (u8)lut;        // integer 0..255, exact
}

// ---------------- Kernel 3: bilinear LUT apply ----------------
// Block = 128 cols x 64 rows (aligned so the (y0,x0) cell is constant).
// The 4 cell-LUTs packed per-bin into ONE u32 -> one ds_read_b32 per pixel
// (4B gather, bank = p mod 32, full 32-bank spread). Interp order matches
// reference exactly: lerp raw 0..255 values, divide by 255 at the end.
__global__ __launch_bounds__(256) void clahe_apply(const u8* __restrict__ pbin,
                                                   const u8* __restrict__ luts8,
                                                   float* __restrict__ out) {
    int rx  = blockIdx.x * 128;
    int ry  = blockIdx.y * 64;
    int img = blockIdx.z;

    int yc = ry + 32, xc = rx + 64;
    int y0 = min(max((int)floorf((yc + 0.5f) * (1.0f / 256.0f) - 0.5f), 0), 7);
    int x0 = min(max((int)floorf((xc + 0.5f) * (1.0f / 256.0f) - 0.5f), 0), 7);
    int y1 = min(y0 + 1, 7), x1 = min(x0 + 1, 7);

    const u8* lb = luts8 + (size_t)img * 64 * NBINS;
    __shared__ u32 s_lutp[NBINS];     // 1 KB
    int t = threadIdx.x;
    {
        u32 b00 = lb[(y0 * 8 + x0) * NBINS + t];
        u32 b01 = lb[(y0 * 8 + x1) * NBINS + t];
        u32 b10 = lb[(y1 * 8 + x0) * NBINS + t];
        u32 b11 = lb[(y1 * 8 + x1) * NBINS + t];
        s_lutp[t] = b00 | (b01 << 8) | (b10 << 16) | (b11 << 24);
    }
    __syncthreads();

    const u8* pbase = pbin + (size_t)img * IMGPX;
    float*    obase = out  + (size_t)img * IMGPX;

    int cg = t & 31, rg = t >> 5;     // 32 lanes * 4 px = 128 cols; 8 rows/iter
    int col = rx + cg * 4;

    float fx0 = (float)x0;
    float wxa[4];
    #pragma unroll
    for (int k = 0; k < 4; ++k) {
        float xs = (col + k + 0.5f) * (1.0f / 256.0f) - 0.5f;
        xs = fminf(fmaxf(xs, 0.0f), 7.0f);
        wxa[k] = xs - fx0;
    }

    #pragma unroll
    for (int it = 0; it < 8; ++it) {
        int row = ry + rg + 8 * it;
        float ys = (row + 0.5f) * (1.0f / 256.0f) - 0.5f;
        ys = fminf(fmaxf(ys, 0.0f), 7.0f);
        float wy = ys - (float)y0;

        size_t off = (size_t)row * W + col;
        u32 pw = *(const u32*)(pbase + off);

        float r[4];
        #pragma unroll
        for (int k = 0; k < 4; ++k) {
            int p = (pw >> (8 * k)) & 255;
            u32 L = s_lutp[p];                      // one ds_read_b32 (4B)
            float f00 = (float)(L & 255);           // v_cvt_f32_ubyte0
            float f01 = (float)((L >> 8) & 255);
            float f10 = (float)((L >> 16) & 255);
            float f11 = (float)(L >> 24);
            float wx = wxa[k];
            float ix0 = (1.0f - wx) * f00 + wx * f01;
            float ix1 = (1.0f - wx) * f10 + wx * f11;
            r[k] = ((1.0f - wy) * ix0 + wy * ix1) * (1.0f / 255.0f);
        }
        f32x4 o = {r[0], r[1], r[2], r[3]};
        __builtin_nontemporal_store(o, (f32x4*)(obase + off));
    }
}

extern "C" void kernel_launch(void* const* d_in, const int* in_sizes, int n_in,
                              void* d_out, int out_size, void* d_ws, size_t ws_size,
                              hipStream_t stream) {
    const float* x = (const float*)d_in[0];
    float* out = (float*)d_out;

    const size_t PBIN_BYTES = (size_t)NIMG * IMGPX;            // 25.17 MB
    const size_t PART_BYTES = (size_t)NTILE * 4 * NBINS * 4;   // 1.57 MB
    u8*  pbin  = (u8*)d_ws;
    u32* part  = (u32*)((char*)d_ws + PBIN_BYTES);
    u8*  luts8 = (u8*)d_ws + PBIN_BYTES + PART_BYTES;          // 98 KB

    clahe_hist<<<dim3(NTILE * 4), dim3(256), 0, stream>>>(x, part, pbin);
    clahe_lut<<<dim3(NTILE), dim3(256), 0, stream>>>(part, luts8);
    clahe_apply<<<dim3(16, 32, NIMG), dim3(256), 0, stream>>>(pbin, luts8, out);
}

// Round 10
// 50.789 us; speedup vs baseline: 1.1776x; 1.0114x over previous
//
#include <hip/hip_runtime.h>

#define H 2048
#define W 2048
#define NBINS 256
#define NIMG 6
#define NTILE 384            // 6 imgs * 64 tiles
#define IMGPX (H * W)

typedef unsigned int u32;
typedef unsigned char u8;
typedef float f32x4 __attribute__((ext_vector_type(4)));

// ---------------- Kernel 1: per-tile partial histograms + pbin ----------------
// 1536 blocks = 4 per tile (64 rows each). Wave-private LDS hists -> plain
// store of the block's partial histogram. x loaded NONTEMPORAL (read exactly
// once; keep cache for pbin). pbin stored normally (re-read by apply).
__global__ __launch_bounds__(256) void clahe_hist(const float* __restrict__ x,
                                                  u32* __restrict__ part,
                                                  u8* __restrict__ pbin) {
    int blk  = blockIdx.x;      // tile*4 + q
    int tile = blk >> 2;
    int q    = blk & 3;
    int tx   = tile & 7;
    int ty   = (tile >> 3) & 7;
    int img  = tile >> 6;
    const float* base = x + (size_t)img * IMGPX;
    u8* pb = pbin + (size_t)img * IMGPX;
    int row0 = ty * 256 + q * 64;
    int col0 = tx * 256;

    __shared__ u32 lh[4][NBINS];
    int t = threadIdx.x;
    for (int i = t; i < 4 * NBINS; i += 256) ((u32*)lh)[i] = 0;
    __syncthreads();

    int w  = t >> 6;    // wave id 0..3
    int cg = t & 63;    // 64 lanes cover 256 cols via float4
    for (int it = 0; it < 16; ++it) {
        int row = row0 + w + 4 * it;
        size_t off = (size_t)row * W + col0 + cg * 4;
        f32x4 v = __builtin_nontemporal_load((const f32x4*)(base + off));
        // hist bins = clip(floor(x*256), 0, 255); x >= 0 so trunc == floor
        int b0 = min((int)(v.x * 256.0f), 255);
        int b1 = min((int)(v.y * 256.0f), 255);
        int b2 = min((int)(v.z * 256.0f), 255);
        int b3 = min((int)(v.w * 256.0f), 255);
        atomicAdd(&lh[w][b0], 1u);
        atomicAdd(&lh[w][b1], 1u);
        atomicAdd(&lh[w][b2], 1u);
        atomicAdd(&lh[w][b3], 1u);
        // pbin = clip(floor(x*255), 0, 255)
        u32 p0 = min((int)(v.x * 255.0f), 255);
        u32 p1 = min((int)(v.y * 255.0f), 255);
        u32 p2 = min((int)(v.z * 255.0f), 255);
        u32 p3 = min((int)(v.w * 255.0f), 255);
        *(u32*)(pb + off) = p0 | (p1 << 8) | (p2 << 16) | (p3 << 24);
    }
    __syncthreads();
    part[(size_t)blk * NBINS + t] =
        lh[0][t] + lh[1][t] + lh[2][t] + lh[3][t];
}

// ---------------- Kernel 2: in-block LUT build + bilinear apply ----------
// Block = 128 cols x 64 rows (aligned so the (y0,x0) cell is constant).
// Wave w builds the LUT of cell w from the partials (exact integer math in
// f32 — verified identical to the standalone LUT kernel, R7/R8). The four
// u8 LUTs are then packed per-bin into ONE u32 -> one ds_read_b32 per pixel
// with full 32-bank spread (R9-proven layout). Line-complete nt stores.
__global__ __launch_bounds__(256) void clahe_apply(const u8* __restrict__ pbin,
                                                   const u32* __restrict__ part,
                                                   float* __restrict__ out) {
    int rx  = blockIdx.x * 128;
    int ry  = blockIdx.y * 64;
    int img = blockIdx.z;

    int yc = ry + 32, xc = rx + 64;
    int y0 = min(max((int)floorf((yc + 0.5f) * (1.0f / 256.0f) - 0.5f), 0), 7);
    int x0 = min(max((int)floorf((xc + 0.5f) * (1.0f / 256.0f) - 0.5f), 0), 7);
    int y1 = min(y0 + 1, 7), x1 = min(x0 + 1, 7);

    __shared__ u32 s_lut8w[4][64];    // wave w's cell LUT, 4 u8 bins / u32
    __shared__ u32 s_lutp[NBINS];     // packed: bin -> {l00,l01,l10,l11}

    int t = threadIdx.x;
    int w = t >> 6, lane = t & 63;

    // ---- wave w: LUT for cell w: (w&2 ? y1 : y0, w&1 ? x1 : x0) ----
    {
        int tys = (w & 2) ? y1 : y0;
        int txs = (w & 1) ? x1 : x0;
        int tile = (img << 6) | (tys << 3) | txs;
        const u32* pb = part + (size_t)tile * 4 * NBINS;
        // lane handles bins 4*lane .. 4*lane+3
        uint4 q0 = *((const uint4*)(pb) + lane);
        uint4 q1 = *((const uint4*)(pb + NBINS) + lane);
        uint4 q2 = *((const uint4*)(pb + 2 * NBINS) + lane);
        uint4 q3 = *((const uint4*)(pb + 3 * NBINS) + lane);
        // counts <= 65536: exact in f32
        float v0 = fminf((float)(q0.x + q1.x + q2.x + q3.x), 10240.0f);
        float v1 = fminf((float)(q0.y + q1.y + q2.y + q3.y), 10240.0f);
        float v2 = fminf((float)(q0.z + q1.z + q2.z + q3.z), 10240.0f);
        float v3 = fminf((float)(q0.w + q1.w + q2.w + q3.w), 10240.0f);
        float c0 = v0, c1 = c0 + v1, c2 = c1 + v2, c3 = c2 + v3;
        // wave-wide scan of per-lane totals
        float s = c3;
        #pragma unroll
        for (int off = 1; off < 64; off <<= 1) {
            float n = __shfl_up(s, off, 64);
            if (lane >= off) s += n;
        }
        float excl = s - c3;
        float tot  = __shfl(s, 63, 64);
        float e = (65536.0f - tot) * (1.0f / 256.0f);   // excess/num_bins
        int bi = 4 * lane;
        const float sc = 255.0f / 65536.0f;
        u32 L0 = (u32)floorf(fminf(fmaxf((excl + c0 + (float)(bi + 1) * e) * sc, 0.0f), 255.0f));
        u32 L1 = (u32)floorf(fminf(fmaxf((excl + c1 + (float)(bi + 2) * e) * sc, 0.0f), 255.0f));
        u32 L2 = (u32)floorf(fminf(fmaxf((excl + c2 + (float)(bi + 3) * e) * sc, 0.0f), 255.0f));
        u32 L3 = (u32)floorf(fminf(fmaxf((excl + c3 + (float)(bi + 4) * e) * sc, 0.0f), 255.0f));
        s_lut8w[w][lane] = L0 | (L1 << 8) | (L2 << 16) | (L3 << 24);
    }
    __syncthreads();
    // ---- pack per-bin across the 4 cells: s_lutp[t] from byte (t&3) ----
    {
        int word = t >> 2, sh = 8 * (t & 3);
        u32 b00 = (s_lut8w[0][word] >> sh) & 255;
        u32 b01 = (s_lut8w[1][word] >> sh) & 255;
        u32 b10 = (s_lut8w[2][word] >> sh) & 255;
        u32 b11 = (s_lut8w[3][word] >> sh) & 255;
        s_lutp[t] = b00 | (b01 << 8) | (b10 << 16) | (b11 << 24);
    }
    __syncthreads();

    const u8* pbase = pbin + (size_t)img * IMGPX;
    float*    obase = out  + (size_t)img * IMGPX;

    int cg = t & 31, rg = t >> 5;     // 32 lanes * 4 px = 128 cols; 8 rows/iter
    int col = rx + cg * 4;

    float fx0 = (float)x0;
    float wxa[4];
    #pragma unroll
    for (int k = 0; k < 4; ++k) {
        float xs = (col + k + 0.5f) * (1.0f / 256.0f) - 0.5f;
        xs = fminf(fmaxf(xs, 0.0f), 7.0f);
        wxa[k] = xs - fx0;
    }

    #pragma unroll
    for (int it = 0; it < 8; ++it) {
        int row = ry + rg + 8 * it;
        float ys = (row + 0.5f) * (1.0f / 256.0f) - 0.5f;
        ys = fminf(fmaxf(ys, 0.0f), 7.0f);
        float wy = ys - (float)y0;

        size_t off = (size_t)row * W + col;
        u32 pw = *(const u32*)(pbase + off);

        float r[4];
        #pragma unroll
        for (int k = 0; k < 4; ++k) {
            int p = (pw >> (8 * k)) & 255;
            u32 L = s_lutp[p];                      // one ds_read_b32 (4B)
            float f00 = (float)(L & 255);           // v_cvt_f32_ubyte0
            float f01 = (float)((L >> 8) & 255);
            float f10 = (float)((L >> 16) & 255);
            float f11 = (float)(L >> 24);
            float wx = wxa[k];
            float ix0 = (1.0f - wx) * f00 + wx * f01;
            float ix1 = (1.0f - wx) * f10 + wx * f11;
            r[k] = ((1.0f - wy) * ix0 + wy * ix1) * (1.0f / 255.0f);
        }
        f32x4 o = {r[0], r[1], r[2], r[3]};
        __builtin_nontemporal_store(o, (f32x4*)(obase + off));
    }
}

extern "C" void kernel_launch(void* const* d_in, const int* in_sizes, int n_in,
                              void* d_out, int out_size, void* d_ws, size_t ws_size,
                              hipStream_t stream) {
    const float* x = (const float*)d_in[0];
    float* out = (float*)d_out;

    const size_t PBIN_BYTES = (size_t)NIMG * IMGPX;            // 25.17 MB
    u8*  pbin = (u8*)d_ws;
    u32* part = (u32*)((char*)d_ws + PBIN_BYTES);              // 1.57 MB

    clahe_hist<<<dim3(NTILE * 4), dim3(256), 0, stream>>>(x, part, pbin);
    clahe_apply<<<dim3(16, 32, NIMG), dim3(256), 0, stream>>>(pbin, part, out);
}

// Round 11
// 49.112 us; speedup vs baseline: 1.2178x; 1.0341x over previous
//
#include <hip/hip_runtime.h>

#define H 2048
#define W 2048
#define NBINS 256
#define NIMG 6
#define NTILE 384            // 6 imgs * 64 tiles
#define IMGPX (H * W)

typedef unsigned int u32;
typedef unsigned char u8;
typedef float f32x4 __attribute__((ext_vector_type(4)));

// ---------------- Kernel 1: per-tile partial histograms + pbin ----------------
// 1536 blocks = 4 per tile (64 rows each). Wave-private LDS hists -> plain
// store of the block's partial histogram. x loaded NONTEMPORAL (read exactly
// once; no-allocate keeps L2 free for pbin). pbin stored normally -> stays in
// this XCD's L2 (3.15 MB/XCD of 4 MB) for apply to re-read.
// Block bid = tile*4+q lands on XCD (4*tx+q)&7 and writes pbin rows
// [64*(4*ty+q),+64) x cols [256*tx,+256) — apply's mapping mirrors this.
__global__ __launch_bounds__(256) void clahe_hist(const float* __restrict__ x,
                                                  u32* __restrict__ part,
                                                  u8* __restrict__ pbin) {
    int blk  = blockIdx.x;      // tile*4 + q
    int tile = blk >> 2;
    int q    = blk & 3;
    int tx   = tile & 7;
    int ty   = (tile >> 3) & 7;
    int img  = tile >> 6;
    const float* base = x + (size_t)img * IMGPX;
    u8* pb = pbin + (size_t)img * IMGPX;
    int row0 = ty * 256 + q * 64;
    int col0 = tx * 256;

    __shared__ u32 lh[4][NBINS];
    int t = threadIdx.x;
    for (int i = t; i < 4 * NBINS; i += 256) ((u32*)lh)[i] = 0;
    __syncthreads();

    int w  = t >> 6;    // wave id 0..3
    int cg = t & 63;    // 64 lanes cover 256 cols via float4
    for (int it = 0; it < 16; ++it) {
        int row = row0 + w + 4 * it;
        size_t off = (size_t)row * W + col0 + cg * 4;
        f32x4 v = __builtin_nontemporal_load((const f32x4*)(base + off));
        // hist bins = clip(floor(x*256), 0, 255); x >= 0 so trunc == floor
        int b0 = min((int)(v.x * 256.0f), 255);
        int b1 = min((int)(v.y * 256.0f), 255);
        int b2 = min((int)(v.z * 256.0f), 255);
        int b3 = min((int)(v.w * 256.0f), 255);
        atomicAdd(&lh[w][b0], 1u);
        atomicAdd(&lh[w][b1], 1u);
        atomicAdd(&lh[w][b2], 1u);
        atomicAdd(&lh[w][b3], 1u);
        // pbin = clip(floor(x*255), 0, 255)
        u32 p0 = min((int)(v.x * 255.0f), 255);
        u32 p1 = min((int)(v.y * 255.0f), 255);
        u32 p2 = min((int)(v.z * 255.0f), 255);
        u32 p3 = min((int)(v.w * 255.0f), 255);
        *(u32*)(pb + off) = p0 | (p1 << 8) | (p2 << 16) | (p3 << 24);
    }
    __syncthreads();
    part[(size_t)blk * NBINS + t] =
        lh[0][t] + lh[1][t] + lh[2][t] + lh[3][t];
}

// ---------------- Kernel 2: in-block LUT build + bilinear apply ----------
// 1D grid of 3072; block->region mapping chosen so each region runs on the
// XCD whose L2 holds its pbin slice (XCD = bid%8 round-robin assumption):
//   v = bid&7 encodes (q = v&3, tx&1 = v>>2); j = bid>>3 encodes the rest.
// Region = 128 cols x 64 rows ((y0,x0) cell constant). Wave w builds the LUT
// of cell w from partials (exact integer math, R7/R8-verified); packed per-bin
// into ONE u32 -> one ds_read_b32/px, 32-bank spread (R9). Line-complete nt
// stores (R6).
__global__ __launch_bounds__(256) void clahe_apply(const u8* __restrict__ pbin,
                                                   const u32* __restrict__ part,
                                                   float* __restrict__ out) {
    int L = blockIdx.x;
    int v5 = L & 7, j = L >> 3;
    int xl  = j & 1;
    int txh = (j >> 1) & 3;
    int yhi = (j >> 3) & 7;
    int img = j >> 6;
    int tx  = txh * 2 + (v5 >> 2);
    int xb  = tx * 2 + xl;           // col block 0..15
    int yb  = yhi * 4 + (v5 & 3);    // row block 0..31 (= 4*ty + q)
    int rx  = xb * 128;
    int ry  = yb * 64;

    int yc = ry + 32, xc = rx + 64;
    int y0 = min(max((int)floorf((yc + 0.5f) * (1.0f / 256.0f) - 0.5f), 0), 7);
    int x0 = min(max((int)floorf((xc + 0.5f) * (1.0f / 256.0f) - 0.5f), 0), 7);
    int y1 = min(y0 + 1, 7), x1 = min(x0 + 1, 7);

    __shared__ u32 s_lut8w[4][64];    // wave w's cell LUT, 4 u8 bins / u32
    __shared__ u32 s_lutp[NBINS];     // packed: bin -> {l00,l01,l10,l11}

    int t = threadIdx.x;
    int w = t >> 6, lane = t & 63;

    // ---- wave w: LUT for cell w: (w&2 ? y1 : y0, w&1 ? x1 : x0) ----
    {
        int tys = (w & 2) ? y1 : y0;
        int txs = (w & 1) ? x1 : x0;
        int tile = (img << 6) | (tys << 3) | txs;
        const u32* pb = part + (size_t)tile * 4 * NBINS;
        // lane handles bins 4*lane .. 4*lane+3
        uint4 q0 = *((const uint4*)(pb) + lane);
        uint4 q1 = *((const uint4*)(pb + NBINS) + lane);
        uint4 q2 = *((const uint4*)(pb + 2 * NBINS) + lane);
        uint4 q3 = *((const uint4*)(pb + 3 * NBINS) + lane);
        // counts <= 65536: exact in f32
        float v0 = fminf((float)(q0.x + q1.x + q2.x + q3.x), 10240.0f);
        float v1 = fminf((float)(q0.y + q1.y + q2.y + q3.y), 10240.0f);
        float v2 = fminf((float)(q0.z + q1.z + q2.z + q3.z), 10240.0f);
        float v3 = fminf((float)(q0.w + q1.w + q2.w + q3.w), 10240.0f);
        float c0 = v0, c1 = c0 + v1, c2 = c1 + v2, c3 = c2 + v3;
        // wave-wide scan of per-lane totals
        float s = c3;
        #pragma unroll
        for (int off = 1; off < 64; off <<= 1) {
            float n = __shfl_up(s, off, 64);
            if (lane >= off) s += n;
        }
        float excl = s - c3;
        float tot  = __shfl(s, 63, 64);
        float e = (65536.0f - tot) * (1.0f / 256.0f);   // excess/num_bins
        int bi = 4 * lane;
        const float sc = 255.0f / 65536.0f;
        u32 L0 = (u32)floorf(fminf(fmaxf((excl + c0 + (float)(bi + 1) * e) * sc, 0.0f), 255.0f));
        u32 L1 = (u32)floorf(fminf(fmaxf((excl + c1 + (float)(bi + 2) * e) * sc, 0.0f), 255.0f));
        u32 L2 = (u32)floorf(fminf(fmaxf((excl + c2 + (float)(bi + 3) * e) * sc, 0.0f), 255.0f));
        u32 L3 = (u32)floorf(fminf(fmaxf((excl + c3 + (float)(bi + 4) * e) * sc, 0.0f), 255.0f));
        s_lut8w[w][lane] = L0 | (L1 << 8) | (L2 << 16) | (L3 << 24);
    }
    __syncthreads();
    // ---- pack per-bin across the 4 cells: s_lutp[t] from byte (t&3) ----
    {
        int word = t >> 2, sh = 8 * (t & 3);
        u32 b00 = (s_lut8w[0][word] >> sh) & 255;
        u32 b01 = (s_lut8w[1][word] >> sh) & 255;
        u32 b10 = (s_lut8w[2][word] >> sh) & 255;
        u32 b11 = (s_lut8w[3][word] >> sh) & 255;
        s_lutp[t] = b00 | (b01 << 8) | (b10 << 16) | (b11 << 24);
    }
    __syncthreads();

    const u8* pbase = pbin + (size_t)img * IMGPX;
    float*    obase = out  + (size_t)img * IMGPX;

    int cg = t & 31, rg = t >> 5;     // 32 lanes * 4 px = 128 cols; 8 rows/iter
    int col = rx + cg * 4;

    float fx0 = (float)x0;
    float wxa[4];
    #pragma unroll
    for (int k = 0; k < 4; ++k) {
        float xs = (col + k + 0.5f) * (1.0f / 256.0f) - 0.5f;
        xs = fminf(fmaxf(xs, 0.0f), 7.0f);
        wxa[k] = xs - fx0;
    }

    #pragma unroll
    for (int it = 0; it < 8; ++it) {
        int row = ry + rg + 8 * it;
        float ys = (row + 0.5f) * (1.0f / 256.0f) - 0.5f;
        ys = fminf(fmaxf(ys, 0.0f), 7.0f);
        float wy = ys - (float)y0;

        size_t off = (size_t)row * W + col;
        u32 pw = *(const u32*)(pbase + off);

        float r[4];
        #pragma unroll
        for (int k = 0; k < 4; ++k) {
            int p = (pw >> (8 * k)) & 255;
            u32 Lp = s_lutp[p];                     // one ds_read_b32 (4B)
            float f00 = (float)(Lp & 255);          // v_cvt_f32_ubyte0
            float f01 = (float)((Lp >> 8) & 255);
            float f10 = (float)((Lp >> 16) & 255);
            float f11 = (float)(Lp >> 24);
            float wx = wxa[k];
            float ix0 = (1.0f - wx) * f00 + wx * f01;
            float ix1 = (1.0f - wx) * f10 + wx * f11;
            r[k] = ((1.0f - wy) * ix0 + wy * ix1) * (1.0f / 255.0f);
        }
        f32x4 o = {r[0], r[1], r[2], r[3]};
        __builtin_nontemporal_store(o, (f32x4*)(obase + off));
    }
}

extern "C" void kernel_launch(void* const* d_in, const int* in_sizes, int n_in,
                              void* d_out, int out_size, void* d_ws, size_t ws_size,
                              hipStream_t stream) {
    const float* x = (const float*)d_in[0];
    float* out = (float*)d_out;

    const size_t PBIN_BYTES = (size_t)NIMG * IMGPX;            // 25.17 MB
    u8*  pbin = (u8*)d_ws;
    u32* part = (u32*)((char*)d_ws + PBIN_BYTES);              // 1.57 MB

    clahe_hist<<<dim3(NTILE * 4), dim3(256), 0, stream>>>(x, part, pbin);
    clahe_apply<<<dim3(16 * 32 * NIMG), dim3(256), 0, stream>>>(pbin, part, out);
}